// Round 10
// baseline (768.919 us; speedup 1.0000x reference)
//
#include <hip/hip_runtime.h>
#include <hip/hip_bf16.h>

#define UN 2048
#define SN 8192
#define NA 10240
#define DN 128
#define SPLITS 8
#define KSPL (NA / SPLITS)  // 1280
#define BK 128
#define KT (KSPL / BK)      // 10
#define BM 160              // grid = 8 x 64 = 512 blocks = 2/CU exactly

typedef __attribute__((ext_vector_type(8))) short bf16x8;
typedef __attribute__((ext_vector_type(4))) float f32x4;
typedef __attribute__((ext_vector_type(8))) int i32x8;

#if __has_builtin(__builtin_amdgcn_mfma_scale_f32_16x16x128_f8f6f4)
#define HAVE_MX 1
#else
#define HAVE_MX 0
#endif

__device__ __forceinline__ unsigned short f2bf(float f) {
  unsigned int u = __builtin_bit_cast(unsigned int, f);
  u += 0x7fffu + ((u >> 16) & 1u);
  return (unsigned short)(u >> 16);
}
__device__ __forceinline__ unsigned int pk2(float a, float b) {
  return (unsigned int)f2bf(a) | ((unsigned int)f2bf(b) << 16);
}

// ---- fp8 e4m3fn packing (scaled upstream) ----
#if __has_builtin(__builtin_amdgcn_cvt_pk_fp8_f32)
__device__ __forceinline__ unsigned int pkfp8_4(float a, float b, float c, float d) {
  int w = __builtin_amdgcn_cvt_pk_fp8_f32(a, b, 0, false);
  w = __builtin_amdgcn_cvt_pk_fp8_f32(c, d, w, true);
  return (unsigned int)w;
}
#else
__device__ __forceinline__ unsigned char f2e4m3(float f) {
  unsigned int u = __builtin_bit_cast(unsigned int, f);
  unsigned int s = (u >> 24) & 0x80u;
  unsigned int a = u & 0x7fffffffu;
  if (a < 0x3c800000u) return (unsigned char)s;
  if (a > 0x43e00000u) a = 0x43e00000u;
  a += 0x7ffffu + ((a >> 20) & 1u);
  unsigned int e = (a >> 23) - 120u;
  unsigned int m = (a >> 20) & 7u;
  if (e > 15u) { e = 15u; m = 6u; }
  return (unsigned char)(s | (e << 3) | m);
}
__device__ __forceinline__ unsigned int pkfp8_4(float a, float b, float c, float d) {
  return (unsigned int)f2e4m3(a) | ((unsigned int)f2e4m3(b) << 8) |
         ((unsigned int)f2e4m3(c) << 16) | ((unsigned int)f2e4m3(d) << 24);
}
#endif

// async global->LDS, 16B per lane
__device__ __forceinline__ void gl_lds16(const void* g, void* l) {
  __builtin_amdgcn_global_load_lds((const __attribute__((address_space(1))) unsigned int*)g,
                                   (__attribute__((address_space(3))) unsigned int*)l, 16, 0, 0);
}
// swizzled LDS helpers (bf16 tiles in k_transform)
__device__ __forceinline__ void st16(unsigned char* base, int row, int cb, int stride, uint4 v) {
  int off = row * stride + cb;
  off ^= (row & 7) << 4;
  *(uint4*)(base + off) = v;
}
__device__ __forceinline__ bf16x8 ld16(const unsigned char* base, int row, int cb, int stride) {
  int off = row * stride + cb;
  off ^= (row & 7) << 4;
  return *(const bf16x8*)(base + off);
}
__device__ __forceinline__ void st2(unsigned char* base, int row, int cb, int stride, unsigned short h) {
  int off = row * stride + cb;
  off ^= (row & 7) << 4;
  *(unsigned short*)(base + off) = h;
}

// prep (fused, block-ranged):
//  [0,25600)        grpha fp32 -> A8 fp8 (x4096), permuted image
//  [25600,26880)    embs_sum = concat(ue,ie)
//  [26880,26904)    W1..3 -> wbf bf16 pre-swizzled
//  [26904,27224)    Bt8 layer-0 from ue/ie (x1024)
// fp8 image: in each 128-k block of row r, granule g (16 k) at byte pos (g^(r&7))*16.
__global__ void k_prep(const float* __restrict__ grpha,
                       const float* __restrict__ ue, const float* __restrict__ ie,
                       const float* __restrict__ W1, const float* __restrict__ W2,
                       const float* __restrict__ W3, unsigned char* __restrict__ A8,
                       float* __restrict__ es, unsigned short* __restrict__ wbf,
                       unsigned char* __restrict__ bt) {
  const int bid = blockIdx.x;
  const int tid = threadIdx.x;
  if (bid < 25600) {
    size_t gid = (size_t)bid * 256 + tid;  // 6,553,600 granules of 16
    int r = (int)(gid / 640);
    int w = (int)(gid % 640);
    int s = w >> 3, g = w & 7;
    const float* p1 = grpha + (size_t)r * NA + s * 128 + g * 16;
    float4 f0 = *(const float4*)p1;
    float4 f1 = *(const float4*)(p1 + 4);
    float4 f2 = *(const float4*)(p1 + 8);
    float4 f3 = *(const float4*)(p1 + 12);
    const float S = 4096.f;
    uint4 o;
    o.x = pkfp8_4(f0.x * S, f0.y * S, f0.z * S, f0.w * S);
    o.y = pkfp8_4(f1.x * S, f1.y * S, f1.z * S, f1.w * S);
    o.z = pkfp8_4(f2.x * S, f2.y * S, f2.z * S, f2.w * S);
    o.w = pkfp8_4(f3.x * S, f3.y * S, f3.z * S, f3.w * S);
    *(uint4*)(A8 + (size_t)r * NA + s * 128 + ((g ^ (r & 7)) * 16)) = o;
  } else if (bid < 26880) {
    int i = (bid - 25600) * 256 + tid;  // float4 over NA*DN/4
    float4 v = (i < UN * DN / 4) ? ((const float4*)ue)[i] : ((const float4*)ie)[i - UN * DN / 4];
    ((float4*)es)[i] = v;
  } else if (bid < 26904) {
    int g = (bid - 26880) * 256 + tid;  // 6144
    int mat = g / 2048;
    int idx = g % 2048;
    int r = idx / 16, cg = idx % 16;
    const float* Wp = (mat == 0) ? W1 : (mat == 1) ? W2 : W3;
    const float4* src = (const float4*)(Wp + (size_t)r * DN + cg * 8);
    float4 a = src[0], b = src[1];
    uint4 w;
    w.x = pk2(a.x, a.y); w.y = pk2(a.z, a.w);
    w.z = pk2(b.x, b.y); w.w = pk2(b.z, b.w);
    *(uint4*)(wbf + (size_t)mat * 16384 + r * 128 + ((cg ^ (r & 7)) * 8)) = w;
  } else {
    int t = (bid - 26904) * 256 + tid;  // 81920 granules
    int c = t & 127;
    int w = t >> 7;
    int kb = w >> 3, g = w & 7;
    const int kbase = kb * 128 + g * 16;
    float v[16];
#pragma unroll
    for (int j = 0; j < 16; j++) {
      int r = kbase + j;
      v[j] = (r < UN) ? ue[(size_t)r * DN + c] : ie[(size_t)(r - UN) * DN + c];
    }
    const float S = 1024.f;
    uint4 o;
    o.x = pkfp8_4(v[0] * S, v[1] * S, v[2] * S, v[3] * S);
    o.y = pkfp8_4(v[4] * S, v[5] * S, v[6] * S, v[7] * S);
    o.z = pkfp8_4(v[8] * S, v[9] * S, v[10] * S, v[11] * S);
    o.w = pkfp8_4(v[12] * S, v[13] * S, v[14] * S, v[15] * S);
    *(uint4*)(bt + (size_t)c * NA + kb * 128 + ((g ^ (c & 7)) * 16)) = o;
  }
}

// part[ks] = A8[m0:m0+160, ks-chunk] @ Bt8[ks-chunk]^T  (fp8 MX MFMA K=128)
// 512 threads = 8 waves (2M x 4N), 2 blocks/CU -> 16 waves/CU (occupancy fix,
// R9 counters: MfmaUtil 13.5%, VALUBusy 5.9%, Occupancy 22.8% -> latency-bound).
// T4 counted-vmcnt double-buffer unchanged.
__global__ __launch_bounds__(512, 4) void k_gemm(const unsigned char* __restrict__ A8,
                                                 const unsigned char* __restrict__ B8,
                                                 unsigned short* __restrict__ part) {
  __shared__ __align__(16) unsigned char As[2][BM * 128];   // 2 x 20 KB
  __shared__ __align__(16) unsigned char Bs[2][128 * 128];  // 2 x 16 KB
  const int ks = blockIdx.x;
  const int m0 = blockIdx.y * BM;
  const int k0 = ks * KSPL;
  const int tid = threadIdx.x;
  const int wave = tid >> 6, lane = tid & 63;
  const int lrow = lane & 15;
  const int kq = lane >> 4;          // 0..3
  const int wr = (wave >> 2) * 80;   // wave row base (0 / 80)
  const int wc = (wave & 3) * 32;    // wave col base (0/32/64/96)
  const int rx = lrow & 7;           // fragment-row swizzle key

  auto stage = [&](int buf, int kt) {
    const int kg = k0 + kt * BK;
    // B: 1024 granules, 2 per thread (2 instr/wave)
#pragma unroll
    for (int j = 0; j < 2; j++) {
      const int L = j * 512 + tid;
      const int row = L >> 3, p = L & 7;
      gl_lds16(B8 + (size_t)row * NA + kg + p * 16, (char*)Bs[buf] + L * 16);
    }
    // A: 1280 granules: 2 per thread + 1 extra for tid<256 (waves 0-3)
#pragma unroll
    for (int j = 0; j < 2; j++) {
      const int L = j * 512 + tid;
      const int row = L >> 3, p = L & 7;
      gl_lds16(A8 + (size_t)(m0 + row) * NA + kg + p * 16, (char*)As[buf] + L * 16);
    }
    if (tid < 256) {
      const int L = 1024 + tid;
      const int row = L >> 3, p = L & 7;
      gl_lds16(A8 + (size_t)(m0 + row) * NA + kg + p * 16, (char*)As[buf] + L * 16);
    }
  };

  f32x4 acc[2][5];  // [fj][fi]
#pragma unroll
  for (int fj = 0; fj < 2; fj++)
#pragma unroll
    for (int fi = 0; fi < 5; fi++) acc[fj][fi] = (f32x4){0.f, 0.f, 0.f, 0.f};

  stage(0, 0);
  int cur = 0;
  for (int kt = 0; kt < KT; kt++) {
    // barrier A: all waves done reading buf[cur^1] -> safe to overwrite
    __builtin_amdgcn_s_barrier();
    if (kt + 1 < KT) {
      stage(cur ^ 1, kt + 1);  // issue next tile (5 instr waves 0-3, 4 instr waves 4-7)
      if (wave < 4) asm volatile("s_waitcnt vmcnt(5)" ::: "memory");
      else          asm volatile("s_waitcnt vmcnt(4)" ::: "memory");
    } else {
      asm volatile("s_waitcnt vmcnt(0)" ::: "memory");
    }
    __builtin_amdgcn_s_barrier();  // all waves' stage(kt) writes visible

#if HAVE_MX
    i32x8 av[5];
#pragma unroll
    for (int fi = 0; fi < 5; fi++) {
      const unsigned char* ab = As[cur] + (wr + fi * 16 + lrow) * 128;
      uint4 lo = *(const uint4*)(ab + (((2 * kq) ^ rx) << 4));
      uint4 hi = *(const uint4*)(ab + (((2 * kq + 1) ^ rx) << 4));
      i32x8 a; a[0] = lo.x; a[1] = lo.y; a[2] = lo.z; a[3] = lo.w;
      a[4] = hi.x; a[5] = hi.y; a[6] = hi.z; a[7] = hi.w;
      av[fi] = a;
    }
#pragma unroll
    for (int fj = 0; fj < 2; fj++) {
      const unsigned char* bb = Bs[cur] + (wc + fj * 16 + lrow) * 128;
      uint4 lo = *(const uint4*)(bb + (((2 * kq) ^ rx) << 4));
      uint4 hi = *(const uint4*)(bb + (((2 * kq + 1) ^ rx) << 4));
      i32x8 b; b[0] = lo.x; b[1] = lo.y; b[2] = lo.z; b[3] = lo.w;
      b[4] = hi.x; b[5] = hi.y; b[6] = hi.z; b[7] = hi.w;
#pragma unroll
      for (int fi = 0; fi < 5; fi++)
        acc[fj][fi] = __builtin_amdgcn_mfma_scale_f32_16x16x128_f8f6f4(
            b, av[fi], acc[fj][fi], 0, 0, 0, 0x7f7f7f7f, 0, 0x7f7f7f7f);
    }
#else
#pragma unroll
    for (int s = 0; s < 4; s++) {
      const int G = 2 * s + (kq >> 1);
      const int boff = ((G ^ rx) << 4) + (kq & 1) * 8;
      long a[5];
#pragma unroll
      for (int fi = 0; fi < 5; fi++)
        a[fi] = *(const long*)(As[cur] + (wr + fi * 16 + lrow) * 128 + boff);
#pragma unroll
      for (int fj = 0; fj < 2; fj++) {
        long b = *(const long*)(Bs[cur] + (wc + fj * 16 + lrow) * 128 + boff);
#pragma unroll
        for (int fi = 0; fi < 5; fi++)
          acc[fj][fi] = __builtin_amdgcn_mfma_f32_16x16x32_fp8_fp8(b, a[fi], acc[fj][fi], 0, 0, 0);
      }
    }
#endif
    cur ^= 1;
  }

  // operand-swapped D: lane holds 4 consecutive n at row m
  unsigned short* op = part + (size_t)ks * NA * DN;
#pragma unroll
  for (int fi = 0; fi < 5; fi++) {
    const size_t mrow = (size_t)(m0 + wr + fi * 16 + lrow) * DN;
#pragma unroll
    for (int fj = 0; fj < 2; fj++) {
      const int n = wc + fj * 16 + kq * 4;
      uint2 pkd;
      pkd.x = pk2(acc[fj][fi][0], acc[fj][fi][1]);
      pkd.y = pk2(acc[fj][fi][2], acc[fj][fi][3]);
      *(uint2*)(op + mrow + n) = pkd;
    }
  }
}

// x = (sum of SPLITS bf16 partials)*scale; 3-layer MLP.
// LAST=0: embs_sum += x, write Bt8 image for next layer.
// LAST=1: sbf = bf16(embs_sum + x)
template <int LAST>
__global__ __launch_bounds__(256) void k_transform(
    const unsigned short* __restrict__ part, float scale,
    const unsigned short* __restrict__ wbf,
    const float* __restrict__ b1, const float* __restrict__ b2, const float* __restrict__ b3,
    float* __restrict__ embs_sum, unsigned char* __restrict__ bt_next,
    unsigned short* __restrict__ sbf) {
  __shared__ __align__(16) unsigned char Ws[2][128 * 128 * 2];  // 2 x 32 KB
  __shared__ __align__(16) unsigned char Xa[32 * 128 * 2];      // 8 KB
  __shared__ __align__(16) unsigned char Xb[32 * 128 * 2];      // 8 KB
  const int r0 = blockIdx.x * 32;
  const int tid = threadIdx.x;
  const int wave = tid >> 6, lane = tid & 63;
  const int lrow = lane & 15;
  const int kq = lane >> 4;
  const int kgrp = kq * 8;
  const int rh = (wave & 1) * 16;
  const int ch = (wave >> 1) * 64;

  auto stage_W = [&](int buf, int s) {
#pragma unroll
    for (int j = 0; j < 8; j++) {
      const int L = j * 256 + tid;
      gl_lds16(wbf + (size_t)s * 16384 + L * 8, (char*)Ws[buf] + L * 16);
    }
  };

  stage_W(0, 0);
  {  // stage input tile into Xa: sum 8 bf16 slabs -> fp32 -> scale -> bf16
    const int xr = tid >> 3, xc = (tid & 7) * 16;
    const size_t base = (size_t)(r0 + xr) * DN + xc;
    float xs[16];
#pragma unroll
    for (int q = 0; q < 16; q++) xs[q] = 0.f;
#pragma unroll
    for (int s = 0; s < SPLITS; s++) {
      const unsigned short* p = part + (size_t)s * NA * DN + base;
      uint4 w1 = *(const uint4*)p;
      uint4 w2 = *(const uint4*)(p + 8);
      const unsigned int wsv[8] = {w1.x, w1.y, w1.z, w1.w, w2.x, w2.y, w2.z, w2.w};
#pragma unroll
      for (int q = 0; q < 8; q++) {
        xs[2 * q]     += __builtin_bit_cast(float, wsv[q] << 16);
        xs[2 * q + 1] += __builtin_bit_cast(float, wsv[q] & 0xffff0000u);
      }
    }
    uint4 w;
    w.x = pk2(xs[0] * scale, xs[1] * scale);   w.y = pk2(xs[2] * scale, xs[3] * scale);
    w.z = pk2(xs[4] * scale, xs[5] * scale);   w.w = pk2(xs[6] * scale, xs[7] * scale);
    st16(Xa, xr, xc * 2, 256, w);
    w.x = pk2(xs[8] * scale, xs[9] * scale);   w.y = pk2(xs[10] * scale, xs[11] * scale);
    w.z = pk2(xs[12] * scale, xs[13] * scale); w.w = pk2(xs[14] * scale, xs[15] * scale);
    st16(Xa, xr, (xc + 8) * 2, 256, w);
  }

  const float* bp[3] = {b1, b2, b3};
  unsigned char* Xin = Xa;
  unsigned char* Xout = Xb;
  int cw = 0;

  for (int s = 0; s < 3; s++) {
    __syncthreads();
    if (s < 2) stage_W(cw ^ 1, s + 1);
    float bb[4];
#pragma unroll
    for (int ct = 0; ct < 4; ct++) bb[ct] = bp[s][ch + ct * 16 + lrow];

    f32x4 acc[4];
#pragma unroll
    for (int i = 0; i < 4; i++) acc[i] = (f32x4){0.f, 0.f, 0.f, 0.f};
#pragma unroll
    for (int kk = 0; kk < 128; kk += 32) {
      bf16x8 af = ld16(Xin, rh + lrow, (kk + kgrp) * 2, 256);
#pragma unroll
      for (int ct = 0; ct < 4; ct++) {
        bf16x8 bf = ld16(Ws[cw], ch + ct * 16 + lrow, (kk + kgrp) * 2, 256);
        acc[ct] = __builtin_amdgcn_mfma_f32_16x16x32_bf16(af, bf, acc[ct], 0, 0, 0);
      }
    }

    if (s < 2) {
#pragma unroll
      for (int ct = 0; ct < 4; ct++)
#pragma unroll
        for (int i = 0; i < 4; i++) {
          int row = rh + kq * 4 + i;
          int col = ch + ct * 16 + lrow;
          float v = acc[ct][i] + bb[ct];
          v = v > 0.f ? v : 0.01f * v;
          st2(Xout, row, col * 2, 256, f2bf(v));
        }
      unsigned char* t = Xin; Xin = Xout; Xout = t;
    } else {
#pragma unroll
      for (int ct = 0; ct < 4; ct++) {
        float tv[4];
#pragma unroll
        for (int i = 0; i < 4; i++) tv[i] = acc[ct][i] + bb[ct];
        const int colg = ch + ct * 16 + lrow;
        const int rbase = r0 + rh + kq * 4;
        if (LAST == 0) {
#pragma unroll
          for (int i = 0; i < 4; i++)
            embs_sum[(size_t)(rbase + i) * DN + colg] += tv[i];
          const float S = 1024.f;
          unsigned int pw = pkfp8_4(tv[0] * S, tv[1] * S, tv[2] * S, tv[3] * S);
          const int g = (rbase & 127) >> 4;
          *(unsigned int*)(bt_next + (size_t)colg * NA + (rbase & ~127) +
                           ((g ^ (colg & 7)) << 4) + (rbase & 15)) = pw;
        } else {
#pragma unroll
          for (int i = 0; i < 4; i++) {
            size_t gi = (size_t)(rbase + i) * DN + colg;
            sbf[gi] = f2bf(embs_sum[gi] + tv[i]);
          }
        }
      }
    }
    cw ^= 1;
  }
}

// fused: pre = (users@items^T)*mask; partial[blk] = sum(w*|pre - tq|)
__global__ __launch_bounds__(256) void k_loss(const unsigned short* __restrict__ sbf,
                                              const float* __restrict__ tq,
                                              const float* __restrict__ lw,
                                              const int* __restrict__ msk,
                                              float* __restrict__ partial) {
  const unsigned short* ubf = sbf;
  const unsigned short* ibf = sbf + (size_t)UN * DN;
  const int r0 = blockIdx.x * 32;
  const int c0 = blockIdx.y * 128;
  const int tid = threadIdx.x;
  const int wave = tid >> 6, lane = tid & 63;
  const int wr = (wave >> 1) * 16;
  const int wc = (wave & 1) * 64;
  const int lrow = lane & 15;
  const int kgrp = (lane >> 4) * 8;

  f32x4 acc[4];
#pragma unroll
  for (int i = 0; i < 4; i++) acc[i] = (f32x4){0.f, 0.f, 0.f, 0.f};
#pragma unroll
  for (int kk = 0; kk < 128; kk += 32) {
    bf16x8 af = *(const bf16x8*)(ubf + (size_t)(r0 + wr + lrow) * DN + kk + kgrp);
#pragma unroll
    for (int ct = 0; ct < 4; ct++) {
      bf16x8 bf = *(const bf16x8*)(ibf + (size_t)(c0 + wc + ct * 16 + lrow) * DN + kk + kgrp);
      acc[ct] = __builtin_amdgcn_mfma_f32_16x16x32_bf16(af, bf, acc[ct], 0, 0, 0);
    }
  }
  float lsum = 0.f;
#pragma unroll
  for (int ct = 0; ct < 4; ct++)
#pragma unroll
    for (int i = 0; i < 4; i++) {
      int r = r0 + wr + (lane >> 4) * 4 + i;
      int c = c0 + wc + ct * 16 + lrow;
      size_t gi = (size_t)r * SN + c;
      float pre = msk[gi] ? acc[ct][i] : 0.f;
      lsum += lw[gi] * fabsf(pre - tq[gi]);
    }
  __shared__ float red[256];
  red[tid] = lsum;
  __syncthreads();
  for (int st = 128; st > 0; st >>= 1) {
    if (tid < st) red[tid] += red[tid + st];
    __syncthreads();
  }
  if (tid == 0) partial[blockIdx.x * 64 + blockIdx.y] = red[0];
}

__global__ void k_reduce(const float* __restrict__ p, float* __restrict__ out) {
  __shared__ float red[256];
  float s = 0.f;
  for (int i = threadIdx.x; i < 4096; i += 256) s += p[i];
  red[threadIdx.x] = s;
  __syncthreads();
  for (int st = 128; st > 0; st >>= 1) {
    if (threadIdx.x < st) red[threadIdx.x] += red[threadIdx.x + st];
    __syncthreads();
  }
  if (threadIdx.x == 0) out[0] = red[0];
}

extern "C" void kernel_launch(void* const* d_in, const int* in_sizes, int n_in,
                              void* d_out, int out_size, void* d_ws, size_t ws_size,
                              hipStream_t stream) {
  const float* user_emb = (const float*)d_in[0];
  const float* item_emb = (const float*)d_in[1];
  const float* grpha    = (const float*)d_in[2];
  const float* W1 = (const float*)d_in[3];
  const float* b1 = (const float*)d_in[4];
  const float* W2 = (const float*)d_in[5];
  const float* b2 = (const float*)d_in[6];
  const float* W3 = (const float*)d_in[7];
  const float* b3 = (const float*)d_in[8];
  const float* tq = (const float*)d_in[9];
  const float* lw = (const float*)d_in[10];
  const int* msk  = (const int*)d_in[11];
  float* out = (float*)d_out;

  char* ws = (char*)d_ws;
  unsigned char* A8 = (unsigned char*)ws;        ws += (size_t)NA * NA;              // 105 MB
  float* embs_sum = (float*)ws;                  ws += (size_t)NA * DN * 4;
  unsigned short* part = (unsigned short*)ws;    ws += (size_t)SPLITS * NA * DN * 2; // 21 MB
  unsigned char* Bt8 = (unsigned char*)ws;       ws += (size_t)DN * NA;              // 1.3 MB
  unsigned short* sbf = (unsigned short*)ws;     ws += (size_t)NA * DN * 2;
  unsigned short* wbf = (unsigned short*)ws;     ws += (size_t)3 * DN * DN * 2;
  float* lpart    = (float*)ws;                  ws += 4096 * 4;

  k_prep<<<27224, 256, 0, stream>>>(grpha, user_emb, item_emb, W1, W2, W3,
                                    A8, embs_sum, wbf, Bt8);
  for (int layer = 0; layer < 3; layer++) {
    k_gemm<<<dim3(SPLITS, NA / BM), 512, 0, stream>>>(A8, Bt8, part);
    float scale = 1.0f / ((1.0f + (float)layer) * 4194304.0f);  // /(1+l)/4096/1024
    if (layer < 2)
      k_transform<0><<<320, 256, 0, stream>>>(part, scale, wbf, b1, b2, b3,
                                              embs_sum, Bt8, sbf);
    else
      k_transform<1><<<320, 256, 0, stream>>>(part, scale, wbf, b1, b2, b3,
                                              embs_sum, Bt8, sbf);
  }
  k_loss<<<dim3(64, 64), 256, 0, stream>>>(sbf, tq, lw, msk, lpart);
  k_reduce<<<1, 256, 0, stream>>>(lpart, out);
}

// Round 11
// 429.153 us; speedup vs baseline: 1.7917x; 1.7917x over previous
//
#include <hip/hip_runtime.h>
#include <hip/hip_bf16.h>

#define UN 2048
#define SN 8192
#define NA 10240
#define DN 128
#define SPLITS 8
#define KSPL (NA / SPLITS)  // 1280
#define BK 128
#define KT (KSPL / BK)      // 10
#define BM 160              // grid = 8 x 64 = 512 blocks = 2/CU exactly

typedef __attribute__((ext_vector_type(8))) short bf16x8;
typedef __attribute__((ext_vector_type(4))) float f32x4;
typedef __attribute__((ext_vector_type(8))) int i32x8;

#if __has_builtin(__builtin_amdgcn_mfma_scale_f32_16x16x128_f8f6f4)
#define HAVE_MX 1
#else
#define HAVE_MX 0
#endif

__device__ __forceinline__ unsigned short f2bf(float f) {
  unsigned int u = __builtin_bit_cast(unsigned int, f);
  u += 0x7fffu + ((u >> 16) & 1u);
  return (unsigned short)(u >> 16);
}
__device__ __forceinline__ unsigned int pk2(float a, float b) {
  return (unsigned int)f2bf(a) | ((unsigned int)f2bf(b) << 16);
}

// ---- fp8 e4m3fn packing (scaled upstream) ----
#if __has_builtin(__builtin_amdgcn_cvt_pk_fp8_f32)
__device__ __forceinline__ unsigned int pkfp8_4(float a, float b, float c, float d) {
  int w = __builtin_amdgcn_cvt_pk_fp8_f32(a, b, 0, false);
  w = __builtin_amdgcn_cvt_pk_fp8_f32(c, d, w, true);
  return (unsigned int)w;
}
#else
__device__ __forceinline__ unsigned char f2e4m3(float f) {
  unsigned int u = __builtin_bit_cast(unsigned int, f);
  unsigned int s = (u >> 24) & 0x80u;
  unsigned int a = u & 0x7fffffffu;
  if (a < 0x3c800000u) return (unsigned char)s;
  if (a > 0x43e00000u) a = 0x43e00000u;
  a += 0x7ffffu + ((a >> 20) & 1u);
  unsigned int e = (a >> 23) - 120u;
  unsigned int m = (a >> 20) & 7u;
  if (e > 15u) { e = 15u; m = 6u; }
  return (unsigned char)(s | (e << 3) | m);
}
__device__ __forceinline__ unsigned int pkfp8_4(float a, float b, float c, float d) {
  return (unsigned int)f2e4m3(a) | ((unsigned int)f2e4m3(b) << 8) |
         ((unsigned int)f2e4m3(c) << 16) | ((unsigned int)f2e4m3(d) << 24);
}
#endif

// async global->LDS, 16B per lane (still used for small W staging in k_transform)
__device__ __forceinline__ void gl_lds16(const void* g, void* l) {
  __builtin_amdgcn_global_load_lds((const __attribute__((address_space(1))) unsigned int*)g,
                                   (__attribute__((address_space(3))) unsigned int*)l, 16, 0, 0);
}
// swizzled LDS helpers (bf16 tiles in k_transform)
__device__ __forceinline__ void st16(unsigned char* base, int row, int cb, int stride, uint4 v) {
  int off = row * stride + cb;
  off ^= (row & 7) << 4;
  *(uint4*)(base + off) = v;
}
__device__ __forceinline__ bf16x8 ld16(const unsigned char* base, int row, int cb, int stride) {
  int off = row * stride + cb;
  off ^= (row & 7) << 4;
  return *(const bf16x8*)(base + off);
}
__device__ __forceinline__ void st2(unsigned char* base, int row, int cb, int stride, unsigned short h) {
  int off = row * stride + cb;
  off ^= (row & 7) << 4;
  *(unsigned short*)(base + off) = h;
}

// prep (fused, block-ranged):
//  [0,25600)        grpha fp32 -> A8 fp8 (x4096), permuted image
//  [25600,26880)    embs_sum = concat(ue,ie)
//  [26880,26904)    W1..3 -> wbf bf16 pre-swizzled
//  [26904,27224)    Bt8 layer-0 from ue/ie (x1024)
// fp8 image: in each 128-k block of row r, granule g (16 k) at byte pos (g^(r&7))*16.
__global__ void k_prep(const float* __restrict__ grpha,
                       const float* __restrict__ ue, const float* __restrict__ ie,
                       const float* __restrict__ W1, const float* __restrict__ W2,
                       const float* __restrict__ W3, unsigned char* __restrict__ A8,
                       float* __restrict__ es, unsigned short* __restrict__ wbf,
                       unsigned char* __restrict__ bt) {
  const int bid = blockIdx.x;
  const int tid = threadIdx.x;
  if (bid < 25600) {
    size_t gid = (size_t)bid * 256 + tid;  // 6,553,600 granules of 16
    int r = (int)(gid / 640);
    int w = (int)(gid % 640);
    int s = w >> 3, g = w & 7;
    const float* p1 = grpha + (size_t)r * NA + s * 128 + g * 16;
    float4 f0 = *(const float4*)p1;
    float4 f1 = *(const float4*)(p1 + 4);
    float4 f2 = *(const float4*)(p1 + 8);
    float4 f3 = *(const float4*)(p1 + 12);
    const float S = 4096.f;
    uint4 o;
    o.x = pkfp8_4(f0.x * S, f0.y * S, f0.z * S, f0.w * S);
    o.y = pkfp8_4(f1.x * S, f1.y * S, f1.z * S, f1.w * S);
    o.z = pkfp8_4(f2.x * S, f2.y * S, f2.z * S, f2.w * S);
    o.w = pkfp8_4(f3.x * S, f3.y * S, f3.z * S, f3.w * S);
    *(uint4*)(A8 + (size_t)r * NA + s * 128 + ((g ^ (r & 7)) * 16)) = o;
  } else if (bid < 26880) {
    int i = (bid - 25600) * 256 + tid;  // float4 over NA*DN/4
    float4 v = (i < UN * DN / 4) ? ((const float4*)ue)[i] : ((const float4*)ie)[i - UN * DN / 4];
    ((float4*)es)[i] = v;
  } else if (bid < 26904) {
    int g = (bid - 26880) * 256 + tid;  // 6144
    int mat = g / 2048;
    int idx = g % 2048;
    int r = idx / 16, cg = idx % 16;
    const float* Wp = (mat == 0) ? W1 : (mat == 1) ? W2 : W3;
    const float4* src = (const float4*)(Wp + (size_t)r * DN + cg * 8);
    float4 a = src[0], b = src[1];
    uint4 w;
    w.x = pk2(a.x, a.y); w.y = pk2(a.z, a.w);
    w.z = pk2(b.x, b.y); w.w = pk2(b.z, b.w);
    *(uint4*)(wbf + (size_t)mat * 16384 + r * 128 + ((cg ^ (r & 7)) * 8)) = w;
  } else {
    int t = (bid - 26904) * 256 + tid;  // 81920 granules
    int c = t & 127;
    int w = t >> 7;
    int kb = w >> 3, g = w & 7;
    const int kbase = kb * 128 + g * 16;
    float v[16];
#pragma unroll
    for (int j = 0; j < 16; j++) {
      int r = kbase + j;
      v[j] = (r < UN) ? ue[(size_t)r * DN + c] : ie[(size_t)(r - UN) * DN + c];
    }
    const float S = 1024.f;
    uint4 o;
    o.x = pkfp8_4(v[0] * S, v[1] * S, v[2] * S, v[3] * S);
    o.y = pkfp8_4(v[4] * S, v[5] * S, v[6] * S, v[7] * S);
    o.z = pkfp8_4(v[8] * S, v[9] * S, v[10] * S, v[11] * S);
    o.w = pkfp8_4(v[12] * S, v[13] * S, v[14] * S, v[15] * S);
    *(uint4*)(bt + (size_t)c * NA + kb * 128 + ((g ^ (c & 7)) * 16)) = o;
  }
}

// part[ks] = A8[m0:m0+160, ks-chunk] @ Bt8[ks-chunk]^T  (fp8 MX MFMA K=128)
// R11 change (single mechanism): staging transport gl_lds -> REG-STAGED
// (global_load_dwordx4 -> uint4 regs, T14 issue-early; vmcnt(0) -> ds_write ->
// lgkmcnt(0) -> barrier). Plain loads pipeline deeply (vmcnt<=63), bypassing
// the gl_lds streaming limit diagnosed in R9 (2.24 TB/s, ~8KB/CU actually in
// flight). Single LDS buffer: the registers are the second buffer.
__global__ __launch_bounds__(256, 2) void k_gemm(const unsigned char* __restrict__ A8,
                                                 const unsigned char* __restrict__ B8,
                                                 unsigned short* __restrict__ part) {
  __shared__ __align__(16) unsigned char As[BM * 128];   // 20 KB
  __shared__ __align__(16) unsigned char Bs[128 * 128];  // 16 KB
  const int ks = blockIdx.x;
  const int m0 = blockIdx.y * BM;
  const int k0 = ks * KSPL;
  const int tid = threadIdx.x;
  const int wave = tid >> 6, lane = tid & 63;
  const int lrow = lane & 15;
  const int kq = lane >> 4;          // 0..3
  const int wr = (wave >> 1) * 80;   // wave row base (0 / 80)
  const int wc = (wave & 1) * 64;    // wave col base
  const int rx = lrow & 7;           // fragment-row swizzle key

  uint4 rA[5], rB[4];                // staged tile in registers
  auto issue_loads = [&](int kt) {   // plain global loads; fly under compute
    const int kg = k0 + kt * BK;
#pragma unroll
    for (int j = 0; j < 5; j++) {
      const int L = j * 256 + tid, row = L >> 3, p = L & 7;
      rA[j] = *(const uint4*)(A8 + (size_t)(m0 + row) * NA + kg + p * 16);
    }
#pragma unroll
    for (int j = 0; j < 4; j++) {
      const int L = j * 256 + tid, row = L >> 3, p = L & 7;
      rB[j] = *(const uint4*)(B8 + (size_t)row * NA + kg + p * 16);
    }
  };
  auto write_lds = [&]() {           // same L-mapping as the old gl_lds dest
#pragma unroll
    for (int j = 0; j < 5; j++) {
      const int L = j * 256 + tid;
      *(uint4*)(As + L * 16) = rA[j];
    }
#pragma unroll
    for (int j = 0; j < 4; j++) {
      const int L = j * 256 + tid;
      *(uint4*)(Bs + L * 16) = rB[j];
    }
  };

  f32x4 acc[4][5];  // [fj][fi]
#pragma unroll
  for (int fj = 0; fj < 4; fj++)
#pragma unroll
    for (int fi = 0; fi < 5; fi++) acc[fj][fi] = (f32x4){0.f, 0.f, 0.f, 0.f};

  issue_loads(0);
  for (int kt = 0; kt < KT; kt++) {
    __builtin_amdgcn_s_barrier();                     // all waves done reading tile(kt-1)
    asm volatile("s_waitcnt vmcnt(0)" ::: "memory");  // regs(kt) landed (issued 1 step ago)
    write_lds();                                      // 9 x ds_write_b128
    if (kt + 1 < KT) issue_loads(kt + 1);             // next tile flies under compute
    asm volatile("s_waitcnt lgkmcnt(0)" ::: "memory");// my ds_writes retired
    __builtin_amdgcn_s_barrier();                     // tile(kt) visible to all waves

#if HAVE_MX
    i32x8 av[5], bv[4];
#pragma unroll
    for (int fi = 0; fi < 5; fi++) {
      const unsigned char* ab = As + (wr + fi * 16 + lrow) * 128;
      uint4 lo = *(const uint4*)(ab + (((2 * kq) ^ rx) << 4));
      uint4 hi = *(const uint4*)(ab + (((2 * kq + 1) ^ rx) << 4));
      i32x8 a; a[0] = lo.x; a[1] = lo.y; a[2] = lo.z; a[3] = lo.w;
      a[4] = hi.x; a[5] = hi.y; a[6] = hi.z; a[7] = hi.w;
      av[fi] = a;
    }
#pragma unroll
    for (int fj = 0; fj < 4; fj++) {
      const unsigned char* bb = Bs + (wc + fj * 16 + lrow) * 128;
      uint4 lo = *(const uint4*)(bb + (((2 * kq) ^ rx) << 4));
      uint4 hi = *(const uint4*)(bb + (((2 * kq + 1) ^ rx) << 4));
      i32x8 b; b[0] = lo.x; b[1] = lo.y; b[2] = lo.z; b[3] = lo.w;
      b[4] = hi.x; b[5] = hi.y; b[6] = hi.z; b[7] = hi.w;
      bv[fj] = b;
    }
#pragma unroll
    for (int fj = 0; fj < 4; fj++)
#pragma unroll
      for (int fi = 0; fi < 5; fi++)
        acc[fj][fi] = __builtin_amdgcn_mfma_scale_f32_16x16x128_f8f6f4(
            bv[fj], av[fi], acc[fj][fi], 0, 0, 0, 0x7f7f7f7f, 0, 0x7f7f7f7f);
#else
#pragma unroll
    for (int s = 0; s < 4; s++) {
      const int G = 2 * s + (kq >> 1);
      const int boff = ((G ^ rx) << 4) + (kq & 1) * 8;
      long a[5], b[4];
#pragma unroll
      for (int fi = 0; fi < 5; fi++)
        a[fi] = *(const long*)(As + (wr + fi * 16 + lrow) * 128 + boff);
#pragma unroll
      for (int fj = 0; fj < 4; fj++)
        b[fj] = *(const long*)(Bs + (wc + fj * 16 + lrow) * 128 + boff);
#pragma unroll
      for (int fj = 0; fj < 4; fj++)
#pragma unroll
        for (int fi = 0; fi < 5; fi++)
          acc[fj][fi] = __builtin_amdgcn_mfma_f32_16x16x32_fp8_fp8(b[fj], a[fi], acc[fj][fi], 0, 0, 0);
    }
#endif
  }

  // operand-swapped D: lane holds 4 consecutive n at row m
  unsigned short* op = part + (size_t)ks * NA * DN;
#pragma unroll
  for (int fi = 0; fi < 5; fi++) {
    const size_t mrow = (size_t)(m0 + wr + fi * 16 + lrow) * DN;
#pragma unroll
    for (int fj = 0; fj < 4; fj++) {
      const int n = wc + fj * 16 + kq * 4;
      uint2 pkd;
      pkd.x = pk2(acc[fj][fi][0], acc[fj][fi][1]);
      pkd.y = pk2(acc[fj][fi][2], acc[fj][fi][3]);
      *(uint2*)(op + mrow + n) = pkd;
    }
  }
}

// x = (sum of SPLITS bf16 partials)*scale; 3-layer MLP.
// LAST=0: embs_sum += x, write Bt8 image for next layer.
// LAST=1: sbf = bf16(embs_sum + x)
template <int LAST>
__global__ __launch_bounds__(256) void k_transform(
    const unsigned short* __restrict__ part, float scale,
    const unsigned short* __restrict__ wbf,
    const float* __restrict__ b1, const float* __restrict__ b2, const float* __restrict__ b3,
    float* __restrict__ embs_sum, unsigned char* __restrict__ bt_next,
    unsigned short* __restrict__ sbf) {
  __shared__ __align__(16) unsigned char Ws[2][128 * 128 * 2];  // 2 x 32 KB
  __shared__ __align__(16) unsigned char Xa[32 * 128 * 2];      // 8 KB
  __shared__ __align__(16) unsigned char Xb[32 * 128 * 2];      // 8 KB
  const int r0 = blockIdx.x * 32;
  const int tid = threadIdx.x;
  const int wave = tid >> 6, lane = tid & 63;
  const int lrow = lane & 15;
  const int kq = lane >> 4;
  const int kgrp = kq * 8;
  const int rh = (wave & 1) * 16;
  const int ch = (wave >> 1) * 64;

  auto stage_W = [&](int buf, int s) {
#pragma unroll
    for (int j = 0; j < 8; j++) {
      const int L = j * 256 + tid;
      gl_lds16(wbf + (size_t)s * 16384 + L * 8, (char*)Ws[buf] + L * 16);
    }
  };

  stage_W(0, 0);
  {  // stage input tile into Xa: sum 8 bf16 slabs -> fp32 -> scale -> bf16
    const int xr = tid >> 3, xc = (tid & 7) * 16;
    const size_t base = (size_t)(r0 + xr) * DN + xc;
    float xs[16];
#pragma unroll
    for (int q = 0; q < 16; q++) xs[q] = 0.f;
#pragma unroll
    for (int s = 0; s < SPLITS; s++) {
      const unsigned short* p = part + (size_t)s * NA * DN + base;
      uint4 w1 = *(const uint4*)p;
      uint4 w2 = *(const uint4*)(p + 8);
      const unsigned int wsv[8] = {w1.x, w1.y, w1.z, w1.w, w2.x, w2.y, w2.z, w2.w};
#pragma unroll
      for (int q = 0; q < 8; q++) {
        xs[2 * q]     += __builtin_bit_cast(float, wsv[q] << 16);
        xs[2 * q + 1] += __builtin_bit_cast(float, wsv[q] & 0xffff0000u);
      }
    }
    uint4 w;
    w.x = pk2(xs[0] * scale, xs[1] * scale);   w.y = pk2(xs[2] * scale, xs[3] * scale);
    w.z = pk2(xs[4] * scale, xs[5] * scale);   w.w = pk2(xs[6] * scale, xs[7] * scale);
    st16(Xa, xr, xc * 2, 256, w);
    w.x = pk2(xs[8] * scale, xs[9] * scale);   w.y = pk2(xs[10] * scale, xs[11] * scale);
    w.z = pk2(xs[12] * scale, xs[13] * scale); w.w = pk2(xs[14] * scale, xs[15] * scale);
    st16(Xa, xr, (xc + 8) * 2, 256, w);
  }

  const float* bp[3] = {b1, b2, b3};
  unsigned char* Xin = Xa;
  unsigned char* Xout = Xb;
  int cw = 0;

  for (int s = 0; s < 3; s++) {
    __syncthreads();
    if (s < 2) stage_W(cw ^ 1, s + 1);
    float bb[4];
#pragma unroll
    for (int ct = 0; ct < 4; ct++) bb[ct] = bp[s][ch + ct * 16 + lrow];

    f32x4 acc[4];
#pragma unroll
    for (int i = 0; i < 4; i++) acc[i] = (f32x4){0.f, 0.f, 0.f, 0.f};
#pragma unroll
    for (int kk = 0; kk < 128; kk += 32) {
      bf16x8 af = ld16(Xin, rh + lrow, (kk + kgrp) * 2, 256);
#pragma unroll
      for (int ct = 0; ct < 4; ct++) {
        bf16x8 bf = ld16(Ws[cw], ch + ct * 16 + lrow, (kk + kgrp) * 2, 256);
        acc[ct] = __builtin_amdgcn_mfma_f32_16x16x32_bf16(af, bf, acc[ct], 0, 0, 0);
      }
    }

    if (s < 2) {
#pragma unroll
      for (int ct = 0; ct < 4; ct++)
#pragma unroll
        for (int i = 0; i < 4; i++) {
          int row = rh + kq * 4 + i;
          int col = ch + ct * 16 + lrow;
          float v = acc[ct][i] + bb[ct];
          v = v > 0.f ? v : 0.01f * v;
          st2(Xout, row, col * 2, 256, f2bf(v));
        }
      unsigned char* t = Xin; Xin = Xout; Xout = t;
    } else {
#pragma unroll
      for (int ct = 0; ct < 4; ct++) {
        float tv[4];
#pragma unroll
        for (int i = 0; i < 4; i++) tv[i] = acc[ct][i] + bb[ct];
        const int colg = ch + ct * 16 + lrow;
        const int rbase = r0 + rh + kq * 4;
        if (LAST == 0) {
#pragma unroll
          for (int i = 0; i < 4; i++)
            embs_sum[(size_t)(rbase + i) * DN + colg] += tv[i];
          const float S = 1024.f;
          unsigned int pw = pkfp8_4(tv[0] * S, tv[1] * S, tv[2] * S, tv[3] * S);
          const int g = (rbase & 127) >> 4;
          *(unsigned int*)(bt_next + (size_t)colg * NA + (rbase & ~127) +
                           ((g ^ (colg & 7)) << 4) + (rbase & 15)) = pw;
        } else {
#pragma unroll
          for (int i = 0; i < 4; i++) {
            size_t gi = (size_t)(rbase + i) * DN + colg;
            sbf[gi] = f2bf(embs_sum[gi] + tv[i]);
          }
        }
      }
    }
    cw ^= 1;
  }
}

// fused: pre = (users@items^T)*mask; partial[blk] = sum(w*|pre - tq|)
__global__ __launch_bounds__(256) void k_loss(const unsigned short* __restrict__ sbf,
                                              const float* __restrict__ tq,
                                              const float* __restrict__ lw,
                                              const int* __restrict__ msk,
                                              float* __restrict__ partial) {
  const unsigned short* ubf = sbf;
  const unsigned short* ibf = sbf + (size_t)UN * DN;
  const int r0 = blockIdx.x * 32;
  const int c0 = blockIdx.y * 128;
  const int tid = threadIdx.x;
  const int wave = tid >> 6, lane = tid & 63;
  const int wr = (wave >> 1) * 16;
  const int wc = (wave & 1) * 64;
  const int lrow = lane & 15;
  const int kgrp = (lane >> 4) * 8;

  f32x4 acc[4];
#pragma unroll
  for (int i = 0; i < 4; i++) acc[i] = (f32x4){0.f, 0.f, 0.f, 0.f};
#pragma unroll
  for (int kk = 0; kk < 128; kk += 32) {
    bf16x8 af = *(const bf16x8*)(ubf + (size_t)(r0 + wr + lrow) * DN + kk + kgrp);
#pragma unroll
    for (int ct = 0; ct < 4; ct++) {
      bf16x8 bf = *(const bf16x8*)(ibf + (size_t)(c0 + wc + ct * 16 + lrow) * DN + kk + kgrp);
      acc[ct] = __builtin_amdgcn_mfma_f32_16x16x32_bf16(af, bf, acc[ct], 0, 0, 0);
    }
  }
  float lsum = 0.f;
#pragma unroll
  for (int ct = 0; ct < 4; ct++)
#pragma unroll
    for (int i = 0; i < 4; i++) {
      int r = r0 + wr + (lane >> 4) * 4 + i;
      int c = c0 + wc + ct * 16 + lrow;
      size_t gi = (size_t)r * SN + c;
      float pre = msk[gi] ? acc[ct][i] : 0.f;
      lsum += lw[gi] * fabsf(pre - tq[gi]);
    }
  __shared__ float red[256];
  red[tid] = lsum;
  __syncthreads();
  for (int st = 128; st > 0; st >>= 1) {
    if (tid < st) red[tid] += red[tid + st];
    __syncthreads();
  }
  if (tid == 0) partial[blockIdx.x * 64 + blockIdx.y] = red[0];
}

__global__ void k_reduce(const float* __restrict__ p, float* __restrict__ out) {
  __shared__ float red[256];
  float s = 0.f;
  for (int i = threadIdx.x; i < 4096; i += 256) s += p[i];
  red[threadIdx.x] = s;
  __syncthreads();
  for (int st = 128; st > 0; st >>= 1) {
    if (threadIdx.x < st) red[threadIdx.x] += red[threadIdx.x + st];
    __syncthreads();
  }
  if (threadIdx.x == 0) out[0] = red[0];
}

extern "C" void kernel_launch(void* const* d_in, const int* in_sizes, int n_in,
                              void* d_out, int out_size, void* d_ws, size_t ws_size,
                              hipStream_t stream) {
  const float* user_emb = (const float*)d_in[0];
  const float* item_emb = (const float*)d_in[1];
  const float* grpha    = (const float*)d_in[2];
  const float* W1 = (const float*)d_in[3];
  const float* b1 = (const float*)d_in[4];
  const float* W2 = (const float*)d_in[5];
  const float* b2 = (const float*)d_in[6];
  const float* W3 = (const float*)d_in[7];
  const float* b3 = (const float*)d_in[8];
  const float* tq = (const float*)d_in[9];
  const float* lw = (const float*)d_in[10];
  const int* msk  = (const int*)d_in[11];
  float* out = (float*)d_out;

  char* ws = (char*)d_ws;
  unsigned char* A8 = (unsigned char*)ws;        ws += (size_t)NA * NA;              // 105 MB
  float* embs_sum = (float*)ws;                  ws += (size_t)NA * DN * 4;
  unsigned short* part = (unsigned short*)ws;    ws += (size_t)SPLITS * NA * DN * 2; // 21 MB
  unsigned char* Bt8 = (unsigned char*)ws;       ws += (size_t)DN * NA;              // 1.3 MB
  unsigned short* sbf = (unsigned short*)ws;     ws += (size_t)NA * DN * 2;
  unsigned short* wbf = (unsigned short*)ws;     ws += (size_t)3 * DN * DN * 2;
  float* lpart    = (float*)ws;                  ws += 4096 * 4;

  k_prep<<<27224, 256, 0, stream>>>(grpha, user_emb, item_emb, W1, W2, W3,
                                    A8, embs_sum, wbf, Bt8);
  for (int layer = 0; layer < 3; layer++) {
    k_gemm<<<dim3(SPLITS, NA / BM), 256, 0, stream>>>(A8, Bt8, part);
    float scale = 1.0f / ((1.0f + (float)layer) * 4194304.0f);  // /(1+l)/4096/1024
    if (layer < 2)
      k_transform<0><<<320, 256, 0, stream>>>(part, scale, wbf, b1, b2, b3,
                                              embs_sum, Bt8, sbf);
    else
      k_transform<1><<<320, 256, 0, stream>>>(part, scale, wbf, b1, b2, b3,
                                              embs_sum, Bt8, sbf);
  }
  k_loss<<<dim3(64, 64), 256, 0, stream>>>(sbf, tq, lw, msk, lpart);
  k_reduce<<<1, 256, 0, stream>>>(lpart, out);
}

// Round 13
// 367.277 us; speedup vs baseline: 2.0936x; 1.1685x over previous
//
#include <hip/hip_runtime.h>
#include <hip/hip_bf16.h>

#define UN 2048
#define SN 8192
#define NA 10240
#define DN 128
#define SPLITS 8
#define KSPL (NA / SPLITS)  // 1280
#define BK 128
#define KT (KSPL / BK)      // 10
#define BM 128              // grid = 8 x 80 = 640 blocks, 3 blocks/CU by LDS

typedef __attribute__((ext_vector_type(8))) short bf16x8;
typedef __attribute__((ext_vector_type(4))) float f32x4;
typedef __attribute__((ext_vector_type(8))) int i32x8;

// __has_builtin is false for amdgcn builtins on the HOST pass (they still
// parse via aux-target); only enforce on the DEVICE pass.
#if defined(__HIP_DEVICE_COMPILE__) && !__has_builtin(__builtin_amdgcn_mfma_scale_f32_16x16x128_f8f6f4)
#error "gfx950 MX MFMA builtin required"
#endif

__device__ __forceinline__ unsigned short f2bf(float f) {
  unsigned int u = __builtin_bit_cast(unsigned int, f);
  u += 0x7fffu + ((u >> 16) & 1u);
  return (unsigned short)(u >> 16);
}
__device__ __forceinline__ unsigned int pk2(float a, float b) {
  return (unsigned int)f2bf(a) | ((unsigned int)f2bf(b) << 16);
}

// ---- fp8 e4m3fn packing (scaled upstream); software fallback is exact RNE ----
__device__ __forceinline__ unsigned char f2e4m3(float f) {
  unsigned int u = __builtin_bit_cast(unsigned int, f);
  unsigned int s = (u >> 24) & 0x80u;
  unsigned int a = u & 0x7fffffffu;
  if (a < 0x3c800000u) return (unsigned char)s;
  if (a > 0x43e00000u) a = 0x43e00000u;
  a += 0x7ffffu + ((a >> 20) & 1u);
  unsigned int e = (a >> 23) - 120u;
  unsigned int m = (a >> 20) & 7u;
  if (e > 15u) { e = 15u; m = 6u; }
  return (unsigned char)(s | (e << 3) | m);
}
__device__ __forceinline__ unsigned int pkfp8_4(float a, float b, float c, float d) {
  return (unsigned int)f2e4m3(a) | ((unsigned int)f2e4m3(b) << 8) |
         ((unsigned int)f2e4m3(c) << 16) | ((unsigned int)f2e4m3(d) << 24);
}

// ---- fp4 e2m1 encode (value pre-scaled into +-6 range), RNE boundaries ----
__device__ __forceinline__ unsigned int f2e2m1(float f) {
  unsigned int s = (__builtin_bit_cast(unsigned int, f) >> 31) << 3;
  float a = fabsf(f);
  unsigned int m = (a < 0.25f) ? 0u : (a < 0.75f) ? 1u : (a < 1.25f) ? 2u
                 : (a < 1.75f) ? 3u : (a < 2.5f) ? 4u : (a < 3.5f) ? 5u
                 : (a < 5.0f) ? 6u : 7u;
  return s | m;
}

// async global->LDS, 16B per lane
__device__ __forceinline__ void gl_lds16(const void* g, void* l) {
  __builtin_amdgcn_global_load_lds((const __attribute__((address_space(1))) unsigned int*)g,
                                   (__attribute__((address_space(3))) unsigned int*)l, 16, 0, 0);
}
// swizzled LDS helpers (bf16 tiles in k_transform)
__device__ __forceinline__ void st16(unsigned char* base, int row, int cb, int stride, uint4 v) {
  int off = row * stride + cb;
  off ^= (row & 7) << 4;
  *(uint4*)(base + off) = v;
}
__device__ __forceinline__ bf16x8 ld16(const unsigned char* base, int row, int cb, int stride) {
  int off = row * stride + cb;
  off ^= (row & 7) << 4;
  return *(const bf16x8*)(base + off);
}
__device__ __forceinline__ void st2(unsigned char* base, int row, int cb, int stride, unsigned short h) {
  int off = row * stride + cb;
  off ^= (row & 7) << 4;
  *(unsigned short*)(base + off) = h;
}

// prep (fused, block-ranged):
//  [0,12800)        grpha fp32 -> A4 fp4 (x64), permuted image
//  [12800,14080)    embs_sum = concat(ue,ie)
//  [14080,14104)    W1..3 -> wbf bf16 pre-swizzled
//  [14104,14424)    Bt8 layer-0 from ue/ie (fp8 x1024)
// A4 image: row r = 5120 B; per 128-k block (64 B) granule g (32 k's, 16 B)
//   at byte pos (g ^ ((r ^ (r>>2)) & 3)) * 16.
// B8 image: row r = 10240 B; per 128-k block granule g (16 k's, 16 B) at
//   byte pos (g ^ (r & 7)) * 16.
__global__ void k_prep(const float* __restrict__ grpha,
                       const float* __restrict__ ue, const float* __restrict__ ie,
                       const float* __restrict__ W1, const float* __restrict__ W2,
                       const float* __restrict__ W3, unsigned char* __restrict__ A4,
                       float* __restrict__ es, unsigned short* __restrict__ wbf,
                       unsigned char* __restrict__ bt) {
  const int bid = blockIdx.x;
  const int tid = threadIdx.x;
  if (bid < 12800) {
    size_t gid = (size_t)bid * 256 + tid;  // 3,276,800 granules of 32 values
    int r = (int)(gid / 320);
    int w = (int)(gid % 320);
    int b = w >> 2, g = w & 3;
    const float* p1 = grpha + (size_t)r * NA + b * 128 + g * 32;
    const float S = 64.f;
    unsigned int ob[4];
#pragma unroll
    for (int q = 0; q < 4; q++) {  // 8 values -> 1 u32 (low nibble = lower k)
      float4 u = *(const float4*)(p1 + q * 8);
      float4 v = *(const float4*)(p1 + q * 8 + 4);
      ob[q] = f2e2m1(u.x * S) | (f2e2m1(u.y * S) << 4) | (f2e2m1(u.z * S) << 8) |
              (f2e2m1(u.w * S) << 12) | (f2e2m1(v.x * S) << 16) | (f2e2m1(v.y * S) << 20) |
              (f2e2m1(v.z * S) << 24) | (f2e2m1(v.w * S) << 28);
    }
    uint4 o = make_uint4(ob[0], ob[1], ob[2], ob[3]);
    const int pos = g ^ ((r ^ (r >> 2)) & 3);
    *(uint4*)(A4 + (size_t)r * (NA / 2) + b * 64 + pos * 16) = o;
  } else if (bid < 14080) {
    int i = (bid - 12800) * 256 + tid;  // float4 over NA*DN/4
    float4 v = (i < UN * DN / 4) ? ((const float4*)ue)[i] : ((const float4*)ie)[i - UN * DN / 4];
    ((float4*)es)[i] = v;
  } else if (bid < 14104) {
    int g = (bid - 14080) * 256 + tid;  // 6144
    int mat = g / 2048;
    int idx = g % 2048;
    int r = idx / 16, cg = idx % 16;
    const float* Wp = (mat == 0) ? W1 : (mat == 1) ? W2 : W3;
    const float4* src = (const float4*)(Wp + (size_t)r * DN + cg * 8);
    float4 a = src[0], b = src[1];
    uint4 w;
    w.x = pk2(a.x, a.y); w.y = pk2(a.z, a.w);
    w.z = pk2(b.x, b.y); w.w = pk2(b.z, b.w);
    *(uint4*)(wbf + (size_t)mat * 16384 + r * 128 + ((cg ^ (r & 7)) * 8)) = w;
  } else {
    int t = (bid - 14104) * 256 + tid;  // 81920 granules
    int c = t & 127;
    int w = t >> 7;
    int kb = w >> 3, g = w & 7;
    const int kbase = kb * 128 + g * 16;
    float v[16];
#pragma unroll
    for (int j = 0; j < 16; j++) {
      int r = kbase + j;
      v[j] = (r < UN) ? ue[(size_t)r * DN + c] : ie[(size_t)(r - UN) * DN + c];
    }
    const float S = 1024.f;
    uint4 o;
    o.x = pkfp8_4(v[0] * S, v[1] * S, v[2] * S, v[3] * S);
    o.y = pkfp8_4(v[4] * S, v[5] * S, v[6] * S, v[7] * S);
    o.z = pkfp8_4(v[8] * S, v[9] * S, v[10] * S, v[11] * S);
    o.w = pkfp8_4(v[12] * S, v[13] * S, v[14] * S, v[15] * S);
    *(uint4*)(bt + (size_t)c * NA + kb * 128 + ((g ^ (c & 7)) * 16)) = o;
  }
}

// part[ks] = A4[m0:m0+128, ks-chunk] @ Bt8[ks-chunk]^T
// MX MFMA K=128, A-operand fp4 (blgp=4), B fp8. T4 counted-vmcnt dbuf (gl_lds).
// LDS 48 KB -> 3 blocks/CU; grid 8 x 80 = 640 blocks.
__global__ __launch_bounds__(256, 3) void k_gemm(const unsigned char* __restrict__ A4,
                                                 const unsigned char* __restrict__ B8,
                                                 unsigned short* __restrict__ part) {
  __shared__ __align__(16) unsigned char As[2][BM * 64];    // 2 x 8 KB (fp4)
  __shared__ __align__(16) unsigned char Bs[2][128 * 128];  // 2 x 16 KB (fp8)
  const int ks = blockIdx.x;
  const int m0 = blockIdx.y * BM;
  const int k0 = ks * KSPL;          // element offset (== B byte offset)
  const int tid = threadIdx.x;
  const int wave = tid >> 6, lane = tid & 63;
  const int lrow = lane & 15;
  const int kq = lane >> 4;          // 0..3
  const int wr = (wave >> 1) * 64;   // wave row base
  const int wc = (wave & 1) * 64;    // wave col base
  const int rx8 = lrow & 7;          // B fragment-row swizzle key

  auto stage = [&](int buf, int kt) {
    const int kg8 = k0 + kt * BK;          // B: bytes == elements
#pragma unroll
    for (int j = 0; j < 4; j++) {
      const int L = j * 256 + tid;         // B granule 0..1023
      const int row = L >> 3, p = L & 7;
      gl_lds16(B8 + (size_t)row * NA + kg8 + p * 16, (char*)Bs[buf] + L * 16);
    }
    const int kg4 = ks * (KSPL / 2) + kt * 64;  // A: fp4 bytes
#pragma unroll
    for (int j = 0; j < 2; j++) {
      const int L = j * 256 + tid;         // A granule 0..511
      const int row = L >> 2, p = L & 3;
      gl_lds16(A4 + (size_t)(m0 + row) * (NA / 2) + kg4 + p * 16, (char*)As[buf] + L * 16);
    }
  };

  f32x4 acc[4][4];  // [fj][fi]
#pragma unroll
  for (int fj = 0; fj < 4; fj++)
#pragma unroll
    for (int fi = 0; fi < 4; fi++) acc[fj][fi] = (f32x4){0.f, 0.f, 0.f, 0.f};

  stage(0, 0);
  int cur = 0;
  for (int kt = 0; kt < KT; kt++) {
    // barrier A: all waves done reading buf[cur^1] -> safe to overwrite
    __builtin_amdgcn_s_barrier();
    if (kt + 1 < KT) {
      stage(cur ^ 1, kt + 1);                           // issue next tile (6 loads)
      asm volatile("s_waitcnt vmcnt(6)" ::: "memory");  // wait only stage(kt)
    } else {
      asm volatile("s_waitcnt vmcnt(0)" ::: "memory");
    }
    __builtin_amdgcn_s_barrier();  // all waves' stage(kt) writes visible

    // A fragments: one 16B read = 32 fp4 = this lane's k-window
    i32x8 av[4];
#pragma unroll
    for (int fi = 0; fi < 4; fi++) {
      const int row = wr + fi * 16 + lrow;
      const int key = (row ^ (row >> 2)) & 3;
      uint4 a4 = *(const uint4*)(As[cur] + row * 64 + ((kq ^ key) << 4));
      i32x8 a; a[0] = a4.x; a[1] = a4.y; a[2] = a4.z; a[3] = a4.w;
      a[4] = 0; a[5] = 0; a[6] = 0; a[7] = 0;
      av[fi] = a;
    }
#pragma unroll
    for (int fj = 0; fj < 4; fj++) {
      const unsigned char* bb = Bs[cur] + (wc + fj * 16 + lrow) * 128;
      uint4 lo = *(const uint4*)(bb + (((2 * kq) ^ rx8) << 4));
      uint4 hi = *(const uint4*)(bb + (((2 * kq + 1) ^ rx8) << 4));
      i32x8 b; b[0] = lo.x; b[1] = lo.y; b[2] = lo.z; b[3] = lo.w;
      b[4] = hi.x; b[5] = hi.y; b[6] = hi.z; b[7] = hi.w;
#pragma unroll
      for (int fi = 0; fi < 4; fi++)
        acc[fj][fi] = __builtin_amdgcn_mfma_scale_f32_16x16x128_f8f6f4(
            b, av[fi], acc[fj][fi], 0 /*cbsz: src0(b)=fp8*/, 4 /*blgp: src1(a)=fp4*/,
            0, 0x7f7f7f7f, 0, 0x7f7f7f7f);
    }
    cur ^= 1;
  }

  // operand-swapped D: lane holds 4 consecutive n at row m
  unsigned short* op = part + (size_t)ks * NA * DN;
#pragma unroll
  for (int fi = 0; fi < 4; fi++) {
    const size_t mrow = (size_t)(m0 + wr + fi * 16 + lrow) * DN;
#pragma unroll
    for (int fj = 0; fj < 4; fj++) {
      const int n = wc + fj * 16 + kq * 4;
      uint2 pkd;
      pkd.x = pk2(acc[fj][fi][0], acc[fj][fi][1]);
      pkd.y = pk2(acc[fj][fi][2], acc[fj][fi][3]);
      *(uint2*)(op + mrow + n) = pkd;
    }
  }
}

// x = (sum of SPLITS bf16 partials)*scale; 3-layer MLP.
// LAST=0: embs_sum += x, write Bt8 image for next layer.
// LAST=1: sbf = bf16(embs_sum + x)
template <int LAST>
__global__ __launch_bounds__(256) void k_transform(
    const unsigned short* __restrict__ part, float scale,
    const unsigned short* __restrict__ wbf,
    const float* __restrict__ b1, const float* __restrict__ b2, const float* __restrict__ b3,
    float* __restrict__ embs_sum, unsigned char* __restrict__ bt_next,
    unsigned short* __restrict__ sbf) {
  __shared__ __align__(16) unsigned char Ws[2][128 * 128 * 2];  // 2 x 32 KB
  __shared__ __align__(16) unsigned char Xa[32 * 128 * 2];      // 8 KB
  __shared__ __align__(16) unsigned char Xb[32 * 128 * 2];      // 8 KB
  const int r0 = blockIdx.x * 32;
  const int tid = threadIdx.x;
  const int wave = tid >> 6, lane = tid & 63;
  const int lrow = lane & 15;
  const int kq = lane >> 4;
  const int kgrp = kq * 8;
  const int rh = (wave & 1) * 16;
  const int ch = (wave >> 1) * 64;

  auto stage_W = [&](int buf, int s) {
#pragma unroll
    for (int j = 0; j < 8; j++) {
      const int L = j * 256 + tid;
      gl_lds16(wbf + (size_t)s * 16384 + L * 8, (char*)Ws[buf] + L * 16);
    }
  };

  stage_W(0, 0);
  {  // stage input tile into Xa: sum 8 bf16 slabs -> fp32 -> scale -> bf16
    const int xr = tid >> 3, xc = (tid & 7) * 16;
    const size_t base = (size_t)(r0 + xr) * DN + xc;
    float xs[16];
#pragma unroll
    for (int q = 0; q < 16; q++) xs[q] = 0.f;
#pragma unroll
    for (int s = 0; s < SPLITS; s++) {
      const unsigned short* p = part + (size_t)s * NA * DN + base;
      uint4 w1 = *(const uint4*)p;
      uint4 w2 = *(const uint4*)(p + 8);
      const unsigned int wsv[8] = {w1.x, w1.y, w1.z, w1.w, w2.x, w2.y, w2.z, w2.w};
#pragma unroll
      for (int q = 0; q < 8; q++) {
        xs[2 * q]     += __builtin_bit_cast(float, wsv[q] << 16);
        xs[2 * q + 1] += __builtin_bit_cast(float, wsv[q] & 0xffff0000u);
      }
    }
    uint4 w;
    w.x = pk2(xs[0] * scale, xs[1] * scale);   w.y = pk2(xs[2] * scale, xs[3] * scale);
    w.z = pk2(xs[4] * scale, xs[5] * scale);   w.w = pk2(xs[6] * scale, xs[7] * scale);
    st16(Xa, xr, xc * 2, 256, w);
    w.x = pk2(xs[8] * scale, xs[9] * scale);   w.y = pk2(xs[10] * scale, xs[11] * scale);
    w.z = pk2(xs[12] * scale, xs[13] * scale); w.w = pk2(xs[14] * scale, xs[15] * scale);
    st16(Xa, xr, (xc + 8) * 2, 256, w);
  }

  const float* bp[3] = {b1, b2, b3};
  unsigned char* Xin = Xa;
  unsigned char* Xout = Xb;
  int cw = 0;

  for (int s = 0; s < 3; s++) {
    __syncthreads();
    if (s < 2) stage_W(cw ^ 1, s + 1);
    float bb[4];
#pragma unroll
    for (int ct = 0; ct < 4; ct++) bb[ct] = bp[s][ch + ct * 16 + lrow];

    f32x4 acc[4];
#pragma unroll
    for (int i = 0; i < 4; i++) acc[i] = (f32x4){0.f, 0.f, 0.f, 0.f};
#pragma unroll
    for (int kk = 0; kk < 128; kk += 32) {
      bf16x8 af = ld16(Xin, rh + lrow, (kk + kgrp) * 2, 256);
#pragma unroll
      for (int ct = 0; ct < 4; ct++) {
        bf16x8 bf = ld16(Ws[cw], ch + ct * 16 + lrow, (kk + kgrp) * 2, 256);
        acc[ct] = __builtin_amdgcn_mfma_f32_16x16x32_bf16(af, bf, acc[ct], 0, 0, 0);
      }
    }

    if (s < 2) {
#pragma unroll
      for (int ct = 0; ct < 4; ct++)
#pragma unroll
        for (int i = 0; i < 4; i++) {
          int row = rh + kq * 4 + i;
          int col = ch + ct * 16 + lrow;
          float v = acc[ct][i] + bb[ct];
          v = v > 0.f ? v : 0.01f * v;
          st2(Xout, row, col * 2, 256, f2bf(v));
        }
      unsigned char* t = Xin; Xin = Xout; Xout = t;
    } else {
#pragma unroll
      for (int ct = 0; ct < 4; ct++) {
        float tv[4];
#pragma unroll
        for (int i = 0; i < 4; i++) tv[i] = acc[ct][i] + bb[ct];
        const int colg = ch + ct * 16 + lrow;
        const int rbase = r0 + rh + kq * 4;
        if (LAST == 0) {
#pragma unroll
          for (int i = 0; i < 4; i++)
            embs_sum[(size_t)(rbase + i) * DN + colg] += tv[i];
          const float S = 1024.f;
          unsigned int pw = pkfp8_4(tv[0] * S, tv[1] * S, tv[2] * S, tv[3] * S);
          const int g = (rbase & 127) >> 4;
          *(unsigned int*)(bt_next + (size_t)colg * NA + (rbase & ~127) +
                           ((g ^ (colg & 7)) << 4) + (rbase & 15)) = pw;
        } else {
#pragma unroll
          for (int i = 0; i < 4; i++) {
            size_t gi = (size_t)(rbase + i) * DN + colg;
            sbf[gi] = f2bf(embs_sum[gi] + tv[i]);
          }
        }
      }
    }
    cw ^= 1;
  }
}

// fused: pre = (users@items^T)*mask; partial[blk] = sum(w*|pre - tq|)
__global__ __launch_bounds__(256) void k_loss(const unsigned short* __restrict__ sbf,
                                              const float* __restrict__ tq,
                                              const float* __restrict__ lw,
                                              const int* __restrict__ msk,
                                              float* __restrict__ partial) {
  const unsigned short* ubf = sbf;
  const unsigned short* ibf = sbf + (size_t)UN * DN;
  const int r0 = blockIdx.x * 32;
  const int c0 = blockIdx.y * 128;
  const int tid = threadIdx.x;
  const int wave = tid >> 6, lane = tid & 63;
  const int wr = (wave >> 1) * 16;
  const int wc = (wave & 1) * 64;
  const int lrow = lane & 15;
  const int kgrp = (lane >> 4) * 8;

  f32x4 acc[4];
#pragma unroll
  for (int i = 0; i < 4; i++) acc[i] = (f32x4){0.f, 0.f, 0.f, 0.f};
#pragma unroll
  for (int kk = 0; kk < 128; kk += 32) {
    bf16x8 af = *(const bf16x8*)(ubf + (size_t)(r0 + wr + lrow) * DN + kk + kgrp);
#pragma unroll
    for (int ct = 0; ct < 4; ct++) {
      bf16x8 bf = *(const bf16x8*)(ibf + (size_t)(c0 + wc + ct * 16 + lrow) * DN + kk + kgrp);
      acc[ct] = __builtin_amdgcn_mfma_f32_16x16x32_bf16(af, bf, acc[ct], 0, 0, 0);
    }
  }
  float lsum = 0.f;
#pragma unroll
  for (int ct = 0; ct < 4; ct++)
#pragma unroll
    for (int i = 0; i < 4; i++) {
      int r = r0 + wr + (lane >> 4) * 4 + i;
      int c = c0 + wc + ct * 16 + lrow;
      size_t gi = (size_t)r * SN + c;
      float pre = msk[gi] ? acc[ct][i] : 0.f;
      lsum += lw[gi] * fabsf(pre - tq[gi]);
    }
  __shared__ float red[256];
  red[tid] = lsum;
  __syncthreads();
  for (int st = 128; st > 0; st >>= 1) {
    if (tid < st) red[tid] += red[tid + st];
    __syncthreads();
  }
  if (tid == 0) partial[blockIdx.x * 64 + blockIdx.y] = red[0];
}

__global__ void k_reduce(const float* __restrict__ p, float* __restrict__ out) {
  __shared__ float red[256];
  float s = 0.f;
  for (int i = threadIdx.x; i < 4096; i += 256) s += p[i];
  red[threadIdx.x] = s;
  __syncthreads();
  for (int st = 128; st > 0; st >>= 1) {
    if (threadIdx.x < st) red[threadIdx.x] += red[threadIdx.x + st];
    __syncthreads();
  }
  if (threadIdx.x == 0) out[0] = red[0];
}

extern "C" void kernel_launch(void* const* d_in, const int* in_sizes, int n_in,
                              void* d_out, int out_size, void* d_ws, size_t ws_size,
                              hipStream_t stream) {
  const float* user_emb = (const float*)d_in[0];
  const float* item_emb = (const float*)d_in[1];
  const float* grpha    = (const float*)d_in[2];
  const float* W1 = (const float*)d_in[3];
  const float* b1 = (const float*)d_in[4];
  const float* W2 = (const float*)d_in[5];
  const float* b2 = (const float*)d_in[6];
  const float* W3 = (const float*)d_in[7];
  const float* b3 = (const float*)d_in[8];
  const float* tq = (const float*)d_in[9];
  const float* lw = (const float*)d_in[10];
  const int* msk  = (const int*)d_in[11];
  float* out = (float*)d_out;

  char* ws = (char*)d_ws;
  unsigned char* A4 = (unsigned char*)ws;        ws += (size_t)NA * NA / 2;          // 52.4 MB
  float* embs_sum = (float*)ws;                  ws += (size_t)NA * DN * 4;
  unsigned short* part = (unsigned short*)ws;    ws += (size_t)SPLITS * NA * DN * 2; // 21 MB
  unsigned char* Bt8 = (unsigned char*)ws;       ws += (size_t)DN * NA;              // 1.3 MB
  unsigned short* sbf = (unsigned short*)ws;     ws += (size_t)NA * DN * 2;
  unsigned short* wbf = (unsigned short*)ws;     ws += (size_t)3 * DN * DN * 2;
  float* lpart    = (float*)ws;                  ws += 4096 * 4;

  k_prep<<<14424, 256, 0, stream>>>(grpha, user_emb, item_emb, W1, W2, W3,
                                    A4, embs_sum, wbf, Bt8);
  for (int layer = 0; layer < 3; layer++) {
    k_gemm<<<dim3(SPLITS, NA / BM), 256, 0, stream>>>(A4, Bt8, part);
    // descale: /(1+l) /64 (A fp4) /1024 (B fp8)
    float scale = 1.0f / ((1.0f + (float)layer) * 65536.0f);
    if (layer < 2)
      k_transform<0><<<320, 256, 0, stream>>>(part, scale, wbf, b1, b2, b3,
                                              embs_sum, Bt8, sbf);
    else
      k_transform<1><<<320, 256, 0, stream>>>(part, scale, wbf, b1, b2, b3,
                                              embs_sum, Bt8, sbf);
  }
  k_loss<<<dim3(64, 64), 256, 0, stream>>>(sbf, tq, lw, msk, lpart);
  k_reduce<<<1, 256, 0, stream>>>(lpart, out);
}

// Round 14
// 315.150 us; speedup vs baseline: 2.4399x; 1.1654x over previous
//
#include <hip/hip_runtime.h>
#include <hip/hip_bf16.h>

#define UN 2048
#define SN 8192
#define NA 10240
#define DN 128
#define SPLITS 8
#define KSPL (NA / SPLITS)  // 1280
#define BK 128
#define KT (KSPL / BK)      // 10
#define BM 160              // grid = 8 x 64 = 512 blocks = 2/CU exactly

typedef __attribute__((ext_vector_type(8))) short bf16x8;
typedef __attribute__((ext_vector_type(4))) float f32x4;
typedef __attribute__((ext_vector_type(8))) int i32x8;

#if defined(__HIP_DEVICE_COMPILE__) && !__has_builtin(__builtin_amdgcn_mfma_scale_f32_16x16x128_f8f6f4)
#error "gfx950 MX MFMA builtin required"
#endif

__device__ __forceinline__ unsigned short f2bf(float f) {
  unsigned int u = __builtin_bit_cast(unsigned int, f);
  u += 0x7fffu + ((u >> 16) & 1u);
  return (unsigned short)(u >> 16);
}
__device__ __forceinline__ unsigned int pk2(float a, float b) {
  return (unsigned int)f2bf(a) | ((unsigned int)f2bf(b) << 16);
}

// ---- fp8 e4m3fn packing (scaled upstream), exact RNE ----
__device__ __forceinline__ unsigned char f2e4m3(float f) {
  unsigned int u = __builtin_bit_cast(unsigned int, f);
  unsigned int s = (u >> 24) & 0x80u;
  unsigned int a = u & 0x7fffffffu;
  if (a < 0x3c800000u) return (unsigned char)s;
  if (a > 0x43e00000u) a = 0x43e00000u;
  a += 0x7ffffu + ((a >> 20) & 1u);
  unsigned int e = (a >> 23) - 120u;
  unsigned int m = (a >> 20) & 7u;
  if (e > 15u) { e = 15u; m = 6u; }
  return (unsigned char)(s | (e << 3) | m);
}
__device__ __forceinline__ unsigned int pkfp8_4(float a, float b, float c, float d) {
  return (unsigned int)f2e4m3(a) | ((unsigned int)f2e4m3(b) << 8) |
         ((unsigned int)f2e4m3(c) << 16) | ((unsigned int)f2e4m3(d) << 24);
}

// async global->LDS, 16B per lane
__device__ __forceinline__ void gl_lds16(const void* g, void* l) {
  __builtin_amdgcn_global_load_lds((const __attribute__((address_space(1))) unsigned int*)g,
                                   (__attribute__((address_space(3))) unsigned int*)l, 16, 0, 0);
}
// swizzled LDS helpers (bf16 tiles in k_transform)
__device__ __forceinline__ void st16(unsigned char* base, int row, int cb, int stride, uint4 v) {
  int off = row * stride + cb;
  off ^= (row & 7) << 4;
  *(uint4*)(base + off) = v;
}
__device__ __forceinline__ bf16x8 ld16(const unsigned char* base, int row, int cb, int stride) {
  int off = row * stride + cb;
  off ^= (row & 7) << 4;
  return *(const bf16x8*)(base + off);
}
__device__ __forceinline__ void st2(unsigned char* base, int row, int cb, int stride, unsigned short h) {
  int off = row * stride + cb;
  off ^= (row & 7) << 4;
  *(unsigned short*)(base + off) = h;
}

// prep (fused, block-ranged): identical to R7.
//  [0,25600)        grpha fp32 -> A8 fp8 (x4096), permuted image
//  [25600,26880)    embs_sum = concat(ue,ie)
//  [26880,26904)    W1..3 -> wbf bf16 pre-swizzled
//  [26904,27224)    Bt8 layer-0 from ue/ie (x1024)
// fp8 image: in each 128-k block of row r, granule g (16 k) at byte pos (g^(r&7))*16.
__global__ void k_prep(const float* __restrict__ grpha,
                       const float* __restrict__ ue, const float* __restrict__ ie,
                       const float* __restrict__ W1, const float* __restrict__ W2,
                       const float* __restrict__ W3, unsigned char* __restrict__ A8,
                       float* __restrict__ es, unsigned short* __restrict__ wbf,
                       unsigned char* __restrict__ bt) {
  const int bid = blockIdx.x;
  const int tid = threadIdx.x;
  if (bid < 25600) {
    size_t gid = (size_t)bid * 256 + tid;
    int r = (int)(gid / 640);
    int w = (int)(gid % 640);
    int s = w >> 3, g = w & 7;
    const float* p1 = grpha + (size_t)r * NA + s * 128 + g * 16;
    float4 f0 = *(const float4*)p1;
    float4 f1 = *(const float4*)(p1 + 4);
    float4 f2 = *(const float4*)(p1 + 8);
    float4 f3 = *(const float4*)(p1 + 12);
    const float S = 4096.f;
    uint4 o;
    o.x = pkfp8_4(f0.x * S, f0.y * S, f0.z * S, f0.w * S);
    o.y = pkfp8_4(f1.x * S, f1.y * S, f1.z * S, f1.w * S);
    o.z = pkfp8_4(f2.x * S, f2.y * S, f2.z * S, f2.w * S);
    o.w = pkfp8_4(f3.x * S, f3.y * S, f3.z * S, f3.w * S);
    *(uint4*)(A8 + (size_t)r * NA + s * 128 + ((g ^ (r & 7)) * 16)) = o;
  } else if (bid < 26880) {
    int i = (bid - 25600) * 256 + tid;
    float4 v = (i < UN * DN / 4) ? ((const float4*)ue)[i] : ((const float4*)ie)[i - UN * DN / 4];
    ((float4*)es)[i] = v;
  } else if (bid < 26904) {
    int g = (bid - 26880) * 256 + tid;
    int mat = g / 2048;
    int idx = g % 2048;
    int r = idx / 16, cg = idx % 16;
    const float* Wp = (mat == 0) ? W1 : (mat == 1) ? W2 : W3;
    const float4* src = (const float4*)(Wp + (size_t)r * DN + cg * 8);
    float4 a = src[0], b = src[1];
    uint4 w;
    w.x = pk2(a.x, a.y); w.y = pk2(a.z, a.w);
    w.z = pk2(b.x, b.y); w.w = pk2(b.z, b.w);
    *(uint4*)(wbf + (size_t)mat * 16384 + r * 128 + ((cg ^ (r & 7)) * 8)) = w;
  } else {
    int t = (bid - 26904) * 256 + tid;
    int c = t & 127;
    int w = t >> 7;
    int kb = w >> 3, g = w & 7;
    const int kbase = kb * 128 + g * 16;
    float v[16];
#pragma unroll
    for (int j = 0; j < 16; j++) {
      int r = kbase + j;
      v[j] = (r < UN) ? ue[(size_t)r * DN + c] : ie[(size_t)(r - UN) * DN + c];
    }
    const float S = 1024.f;
    uint4 o;
    o.x = pkfp8_4(v[0] * S, v[1] * S, v[2] * S, v[3] * S);
    o.y = pkfp8_4(v[4] * S, v[5] * S, v[6] * S, v[7] * S);
    o.z = pkfp8_4(v[8] * S, v[9] * S, v[10] * S, v[11] * S);
    o.w = pkfp8_4(v[12] * S, v[13] * S, v[14] * S, v[15] * S);
    *(uint4*)(bt + (size_t)c * NA + kb * 128 + ((g ^ (c & 7)) * 16)) = o;
  }
}

// part[ks] = A8[m0:m0+160, ks-chunk] @ Bt8[ks-chunk]^T  (fp8 MX MFMA K=128)
// R14 single change vs R7: A is DIRECT-TO-REGISTER (plain global loads, proven
// 6.3 TB/s class vs gl_lds' measured 2.2-2.9 here), loaded one K-step ahead
// into a statically-rotated register pair; LDS + barriers only serve B.
// A addresses use the same permuted-image offsets -> MFMA inputs bit-identical.
__global__ __launch_bounds__(256, 2) void k_gemm(const unsigned char* __restrict__ A8,
                                                 const unsigned char* __restrict__ B8,
                                                 unsigned short* __restrict__ part) {
  __shared__ __align__(16) unsigned char Bs[2][128 * 128];  // 2 x 16 KB
  const int ks = blockIdx.x;
  const int m0 = blockIdx.y * BM;
  const int k0 = ks * KSPL;
  const int tid = threadIdx.x;
  const int wave = tid >> 6, lane = tid & 63;
  const int lrow = lane & 15;
  const int kq = lane >> 4;          // 0..3
  const int wr = (wave >> 1) * 80;   // wave row base (0 / 80)
  const int wc = (wave & 1) * 64;    // wave col base
  const int rx = lrow & 7;           // fragment-row swizzle key (row&7 == lrow&7)

  auto stageB = [&](int buf, int kt) {
    const int kg = k0 + kt * BK;
#pragma unroll
    for (int j = 0; j < 4; j++) {
      const int L = j * 256 + tid;   // B granule 0..1023
      const int row = L >> 3, p = L & 7;
      gl_lds16(B8 + (size_t)row * NA + kg + p * 16, (char*)Bs[buf] + L * 16);
    }
  };
  auto loadA = [&](uint4 (&r)[5][2], int kt) {  // 10 plain loads -> regs
    const int kg = k0 + kt * BK;
#pragma unroll
    for (int fi = 0; fi < 5; fi++) {
      const unsigned char* ab = A8 + (size_t)(m0 + wr + fi * 16 + lrow) * NA + kg;
      r[fi][0] = *(const uint4*)(ab + (((2 * kq) ^ rx) << 4));
      r[fi][1] = *(const uint4*)(ab + (((2 * kq + 1) ^ rx) << 4));
    }
  };

  uint4 rA0[5][2], rA1[5][2];  // ping-pong, statically indexed via unroll

  f32x4 acc[4][5];  // [fj][fi]
#pragma unroll
  for (int fj = 0; fj < 4; fj++)
#pragma unroll
    for (int fi = 0; fi < 5; fi++) acc[fj][fi] = (f32x4){0.f, 0.f, 0.f, 0.f};

  stageB(0, 0);
  loadA(rA0, 0);
#pragma unroll
  for (int kt = 0; kt < KT; kt++) {
    uint4(&rCur)[5][2] = (kt & 1) ? rA1 : rA0;
    uint4(&rNxt)[5][2] = (kt & 1) ? rA0 : rA1;
    const int cur = kt & 1;
    // barrier A: all waves done reading Bs[cur^1] -> safe to overwrite
    __builtin_amdgcn_s_barrier();
    if (kt + 1 < KT) {
      stageB(cur ^ 1, kt + 1);   // 4 gl_lds
      loadA(rNxt, kt + 1);       // 10 plain loads
      asm volatile("s_waitcnt vmcnt(14)" ::: "memory");  // B(kt)+A(kt) landed
    } else {
      asm volatile("s_waitcnt vmcnt(0)" ::: "memory");
    }
    __builtin_amdgcn_s_barrier();  // Bs[cur] visible to all waves

    i32x8 av[5], bv[4];
#pragma unroll
    for (int fi = 0; fi < 5; fi++) {
      uint4 lo = rCur[fi][0], hi = rCur[fi][1];
      i32x8 a; a[0] = lo.x; a[1] = lo.y; a[2] = lo.z; a[3] = lo.w;
      a[4] = hi.x; a[5] = hi.y; a[6] = hi.z; a[7] = hi.w;
      av[fi] = a;
    }
#pragma unroll
    for (int fj = 0; fj < 4; fj++) {
      const unsigned char* bb = Bs[cur] + (wc + fj * 16 + lrow) * 128;
      uint4 lo = *(const uint4*)(bb + (((2 * kq) ^ rx) << 4));
      uint4 hi = *(const uint4*)(bb + (((2 * kq + 1) ^ rx) << 4));
      i32x8 b; b[0] = lo.x; b[1] = lo.y; b[2] = lo.z; b[3] = lo.w;
      b[4] = hi.x; b[5] = hi.y; b[6] = hi.z; b[7] = hi.w;
      bv[fj] = b;
    }
#pragma unroll
    for (int fj = 0; fj < 4; fj++)
#pragma unroll
      for (int fi = 0; fi < 5; fi++)
        acc[fj][fi] = __builtin_amdgcn_mfma_scale_f32_16x16x128_f8f6f4(
            bv[fj], av[fi], acc[fj][fi], 0, 0, 0, 0x7f7f7f7f, 0, 0x7f7f7f7f);
  }

  // operand-swapped D: lane holds 4 consecutive n at row m
  unsigned short* op = part + (size_t)ks * NA * DN;
#pragma unroll
  for (int fi = 0; fi < 5; fi++) {
    const size_t mrow = (size_t)(m0 + wr + fi * 16 + lrow) * DN;
#pragma unroll
    for (int fj = 0; fj < 4; fj++) {
      const int n = wc + fj * 16 + kq * 4;
      uint2 pkd;
      pkd.x = pk2(acc[fj][fi][0], acc[fj][fi][1]);
      pkd.y = pk2(acc[fj][fi][2], acc[fj][fi][3]);
      *(uint2*)(op + mrow + n) = pkd;
    }
  }
}

// x = (sum of SPLITS bf16 partials)*scale; 3-layer MLP.  (identical to R7)
// LAST=0: embs_sum += x, write Bt8 image for next layer.
// LAST=1: sbf = bf16(embs_sum + x)
template <int LAST>
__global__ __launch_bounds__(256) void k_transform(
    const unsigned short* __restrict__ part, float scale,
    const unsigned short* __restrict__ wbf,
    const float* __restrict__ b1, const float* __restrict__ b2, const float* __restrict__ b3,
    float* __restrict__ embs_sum, unsigned char* __restrict__ bt_next,
    unsigned short* __restrict__ sbf) {
  __shared__ __align__(16) unsigned char Ws[2][128 * 128 * 2];  // 2 x 32 KB
  __shared__ __align__(16) unsigned char Xa[32 * 128 * 2];      // 8 KB
  __shared__ __align__(16) unsigned char Xb[32 * 128 * 2];      // 8 KB
  const int r0 = blockIdx.x * 32;
  const int tid = threadIdx.x;
  const int wave = tid >> 6, lane = tid & 63;
  const int lrow = lane & 15;
  const int kq = lane >> 4;
  const int kgrp = kq * 8;
  const int rh = (wave & 1) * 16;
  const int ch = (wave >> 1) * 64;

  auto stage_W = [&](int buf, int s) {
#pragma unroll
    for (int j = 0; j < 8; j++) {
      const int L = j * 256 + tid;
      gl_lds16(wbf + (size_t)s * 16384 + L * 8, (char*)Ws[buf] + L * 16);
    }
  };

  stage_W(0, 0);
  {  // stage input tile into Xa: sum 8 bf16 slabs -> fp32 -> scale -> bf16
    const int xr = tid >> 3, xc = (tid & 7) * 16;
    const size_t base = (size_t)(r0 + xr) * DN + xc;
    float xs[16];
#pragma unroll
    for (int q = 0; q < 16; q++) xs[q] = 0.f;
#pragma unroll
    for (int s = 0; s < SPLITS; s++) {
      const unsigned short* p = part + (size_t)s * NA * DN + base;
      uint4 w1 = *(const uint4*)p;
      uint4 w2 = *(const uint4*)(p + 8);
      const unsigned int wsv[8] = {w1.x, w1.y, w1.z, w1.w, w2.x, w2.y, w2.z, w2.w};
#pragma unroll
      for (int q = 0; q < 8; q++) {
        xs[2 * q]     += __builtin_bit_cast(float, wsv[q] << 16);
        xs[2 * q + 1] += __builtin_bit_cast(float, wsv[q] & 0xffff0000u);
      }
    }
    uint4 w;
    w.x = pk2(xs[0] * scale, xs[1] * scale);   w.y = pk2(xs[2] * scale, xs[3] * scale);
    w.z = pk2(xs[4] * scale, xs[5] * scale);   w.w = pk2(xs[6] * scale, xs[7] * scale);
    st16(Xa, xr, xc * 2, 256, w);
    w.x = pk2(xs[8] * scale, xs[9] * scale);   w.y = pk2(xs[10] * scale, xs[11] * scale);
    w.z = pk2(xs[12] * scale, xs[13] * scale); w.w = pk2(xs[14] * scale, xs[15] * scale);
    st16(Xa, xr, (xc + 8) * 2, 256, w);
  }

  const float* bp[3] = {b1, b2, b3};
  unsigned char* Xin = Xa;
  unsigned char* Xout = Xb;
  int cw = 0;

  for (int s = 0; s < 3; s++) {
    __syncthreads();
    if (s < 2) stage_W(cw ^ 1, s + 1);
    float bb[4];
#pragma unroll
    for (int ct = 0; ct < 4; ct++) bb[ct] = bp[s][ch + ct * 16 + lrow];

    f32x4 acc[4];
#pragma unroll
    for (int i = 0; i < 4; i++) acc[i] = (f32x4){0.f, 0.f, 0.f, 0.f};
#pragma unroll
    for (int kk = 0; kk < 128; kk += 32) {
      bf16x8 af = ld16(Xin, rh + lrow, (kk + kgrp) * 2, 256);
#pragma unroll
      for (int ct = 0; ct < 4; ct++) {
        bf16x8 bf = ld16(Ws[cw], ch + ct * 16 + lrow, (kk + kgrp) * 2, 256);
        acc[ct] = __builtin_amdgcn_mfma_f32_16x16x32_bf16(af, bf, acc[ct], 0, 0, 0);
      }
    }

    if (s < 2) {
#pragma unroll
      for (int ct = 0; ct < 4; ct++)
#pragma unroll
        for (int i = 0; i < 4; i++) {
          int row = rh + kq * 4 + i;
          int col = ch + ct * 16 + lrow;
          float v = acc[ct][i] + bb[ct];
          v = v > 0.f ? v : 0.01f * v;
          st2(Xout, row, col * 2, 256, f2bf(v));
        }
      unsigned char* t = Xin; Xin = Xout; Xout = t;
    } else {
#pragma unroll
      for (int ct = 0; ct < 4; ct++) {
        float tv[4];
#pragma unroll
        for (int i = 0; i < 4; i++) tv[i] = acc[ct][i] + bb[ct];
        const int colg = ch + ct * 16 + lrow;
        const int rbase = r0 + rh + kq * 4;
        if (LAST == 0) {
#pragma unroll
          for (int i = 0; i < 4; i++)
            embs_sum[(size_t)(rbase + i) * DN + colg] += tv[i];
          const float S = 1024.f;
          unsigned int pw = pkfp8_4(tv[0] * S, tv[1] * S, tv[2] * S, tv[3] * S);
          const int g = (rbase & 127) >> 4;
          *(unsigned int*)(bt_next + (size_t)colg * NA + (rbase & ~127) +
                           ((g ^ (colg & 7)) << 4) + (rbase & 15)) = pw;
        } else {
#pragma unroll
          for (int i = 0; i < 4; i++) {
            size_t gi = (size_t)(rbase + i) * DN + colg;
            sbf[gi] = f2bf(embs_sum[gi] + tv[i]);
          }
        }
      }
    }
    cw ^= 1;
  }
}

// fused: pre = (users@items^T)*mask; partial[blk] = sum(w*|pre - tq|)
__global__ __launch_bounds__(256) void k_loss(const unsigned short* __restrict__ sbf,
                                              const float* __restrict__ tq,
                                              const float* __restrict__ lw,
                                              const int* __restrict__ msk,
                                              float* __restrict__ partial) {
  const unsigned short* ubf = sbf;
  const unsigned short* ibf = sbf + (size_t)UN * DN;
  const int r0 = blockIdx.x * 32;
  const int c0 = blockIdx.y * 128;
  const int tid = threadIdx.x;
  const int wave = tid >> 6, lane = tid & 63;
  const int wr = (wave >> 1) * 16;
  const int wc = (wave & 1) * 64;
  const int lrow = lane & 15;
  const int kgrp = (lane >> 4) * 8;

  f32x4 acc[4];
#pragma unroll
  for (int i = 0; i < 4; i++) acc[i] = (f32x4){0.f, 0.f, 0.f, 0.f};
#pragma unroll
  for (int kk = 0; kk < 128; kk += 32) {
    bf16x8 af = *(const bf16x8*)(ubf + (size_t)(r0 + wr + lrow) * DN + kk + kgrp);
#pragma unroll
    for (int ct = 0; ct < 4; ct++) {
      bf16x8 bf = *(const bf16x8*)(ibf + (size_t)(c0 + wc + ct * 16 + lrow) * DN + kk + kgrp);
      acc[ct] = __builtin_amdgcn_mfma_f32_16x16x32_bf16(af, bf, acc[ct], 0, 0, 0);
    }
  }
  float lsum = 0.f;
#pragma unroll
  for (int ct = 0; ct < 4; ct++)
#pragma unroll
    for (int i = 0; i < 4; i++) {
      int r = r0 + wr + (lane >> 4) * 4 + i;
      int c = c0 + wc + ct * 16 + lrow;
      size_t gi = (size_t)r * SN + c;
      float pre = msk[gi] ? acc[ct][i] : 0.f;
      lsum += lw[gi] * fabsf(pre - tq[gi]);
    }
  __shared__ float red[256];
  red[tid] = lsum;
  __syncthreads();
  for (int st = 128; st > 0; st >>= 1) {
    if (tid < st) red[tid] += red[tid + st];
    __syncthreads();
  }
  if (tid == 0) partial[blockIdx.x * 64 + blockIdx.y] = red[0];
}

__global__ void k_reduce(const float* __restrict__ p, float* __restrict__ out) {
  __shared__ float red[256];
  float s = 0.f;
  for (int i = threadIdx.x; i < 4096; i += 256) s += p[i];
  red[threadIdx.x] = s;
  __syncthreads();
  for (int st = 128; st > 0; st >>= 1) {
    if (threadIdx.x < st) red[threadIdx.x] += red[threadIdx.x + st];
    __syncthreads();
  }
  if (threadIdx.x == 0) out[0] = red[0];
}

extern "C" void kernel_launch(void* const* d_in, const int* in_sizes, int n_in,
                              void* d_out, int out_size, void* d_ws, size_t ws_size,
                              hipStream_t stream) {
  const float* user_emb = (const float*)d_in[0];
  const float* item_emb = (const float*)d_in[1];
  const float* grpha    = (const float*)d_in[2];
  const float* W1 = (const float*)d_in[3];
  const float* b1 = (const float*)d_in[4];
  const float* W2 = (const float*)d_in[5];
  const float* b2 = (const float*)d_in[6];
  const float* W3 = (const float*)d_in[7];
  const float* b3 = (const float*)d_in[8];
  const float* tq = (const float*)d_in[9];
  const float* lw = (const float*)d_in[10];
  const int* msk  = (const int*)d_in[11];
  float* out = (float*)d_out;

  char* ws = (char*)d_ws;
  unsigned char* A8 = (unsigned char*)ws;        ws += (size_t)NA * NA;              // 105 MB
  float* embs_sum = (float*)ws;                  ws += (size_t)NA * DN * 4;
  unsigned short* part = (unsigned short*)ws;    ws += (size_t)SPLITS * NA * DN * 2; // 21 MB
  unsigned char* Bt8 = (unsigned char*)ws;       ws += (size_t)DN * NA;              // 1.3 MB
  unsigned short* sbf = (unsigned short*)ws;     ws += (size_t)NA * DN * 2;
  unsigned short* wbf = (unsigned short*)ws;     ws += (size_t)3 * DN * DN * 2;
  float* lpart    = (float*)ws;                  ws += 4096 * 4;

  k_prep<<<27224, 256, 0, stream>>>(grpha, user_emb, item_emb, W1, W2, W3,
                                    A8, embs_sum, wbf, Bt8);
  for (int layer = 0; layer < 3; layer++) {
    k_gemm<<<dim3(SPLITS, NA / BM), 256, 0, stream>>>(A8, Bt8, part);
    float scale = 1.0f / ((1.0f + (float)layer) * 4194304.0f);  // /(1+l)/4096/1024
    if (layer < 2)
      k_transform<0><<<320, 256, 0, stream>>>(part, scale, wbf, b1, b2, b3,
                                              embs_sum, Bt8, sbf);
    else
      k_transform<1><<<320, 256, 0, stream>>>(part, scale, wbf, b1, b2, b3,
                                              embs_sum, Bt8, sbf);
  }
  k_loss<<<dim3(64, 64), 256, 0, stream>>>(sbf, tq, lw, msk, lpart);
  k_reduce<<<1, 256, 0, stream>>>(lpart, out);
}